// Round 5
// baseline (82.282 us; speedup 1.0000x reference)
//
#include <hip/hip_runtime.h>

#define Bsz 64
#define Ssz 512
#define Hsz 768
#define Tsz 9
#define NCH 16
#define CHW 32
#define LOG2E 1.4426950408889634f
#define LN2F  0.6931471805599453f

__device__ __forceinline__ int SK(int s) { return s * Tsz + ((s >> 5) << 1); }

// ============ K1: fused emissions GEMM + chunk transfer-matrix scans ============
// grid = B*NCH = 1024 blocks x 256 threads. Block (b,c): computes em rows
// [c*32, c*32+32] (33 rows, 8 lanes/row), writes rows [c*32, c*32+31] to global,
// then wave0 runs the LSE chunk scan, wave1 the Viterbi max-plus chunk scan.
__global__ __launch_bounds__(256, 1) void emscan_kernel(
    const float* __restrict__ x, const float* __restrict__ fcw,
    const float* __restrict__ fcb, const int* __restrict__ mask,
    const float* __restrict__ trans, float* __restrict__ em,
    float* __restrict__ R2, float* __restrict__ MV, int* __restrict__ cnt) {
    __shared__ __align__(16) float4 w4[Tsz * Hsz / 4];   // 27648 B
    __shared__ float bias[Tsz];
    __shared__ float em_w[33 * Tsz];
    __shared__ int mk_w[33];

    const int tid = threadIdx.x;
    const int bc = blockIdx.x;
    const int b = bc >> 4, c = bc & 15;
    const int base = c * CHW;

    if (bc == 0 && tid == 0) *cnt = 0;   // zero the last-block counter for vit3

    const float4* fw4 = reinterpret_cast<const float4*>(fcw);
#pragma unroll
    for (int i = 0; i < 7; ++i) {
        const int o = tid + i * 256;
        if (o < 1728) w4[o] = fw4[o];
    }
    if (tid < Tsz) bias[tid] = fcb[tid];
    if (tid < 33) {
        const int s = base + tid;
        mk_w[tid] = (s < Ssz) ? mask[b * Ssz + s] : 0;
    }
    __syncthreads();

    const int l = tid & 7;
    // ---- GEMM: row r = tid>>3 (0..31); threads 192..199 also do row 32 ----
    {
        const int r = tid >> 3;
        int rr = r;
        int extra = 0;
        do {
            const float4* xr = reinterpret_cast<const float4*>(
                x + ((size_t)b * Ssz + base + rr) * Hsz);
            float acc[Tsz];
#pragma unroll
            for (int t = 0; t < Tsz; ++t) acc[t] = 0.0f;
#pragma unroll 4
            for (int i = 0; i < 24; ++i) {
                const float4 xv = xr[i * 8 + l];
#pragma unroll
                for (int t = 0; t < Tsz; ++t) {
                    const float4 wv = w4[t * 192 + i * 8 + l];
                    acc[t] = fmaf(xv.x, wv.x, fmaf(xv.y, wv.y,
                             fmaf(xv.z, wv.z, fmaf(xv.w, wv.w, acc[t]))));
                }
            }
#pragma unroll
            for (int t = 0; t < Tsz; ++t) {
                acc[t] += __shfl_xor(acc[t], 1, 64);
                acc[t] += __shfl_xor(acc[t], 2, 64);
                acc[t] += __shfl_xor(acc[t], 4, 64);
            }
#pragma unroll
            for (int t = 0; t < 8; ++t)
                if (l == t) em_w[rr * Tsz + t] = acc[t] + bias[t];
            if (l == 0) em_w[rr * Tsz + 8] = acc[8] + bias[8];
            // row-32 overlap pass on threads 192..199 (identical code path ->
            // bit-identical to block c+1's row 0)
            extra = (!extra && tid >= 192 && tid < 200 && base + CHW < Ssz);
            rr = CHW;
        } while (extra);
    }
    __syncthreads();

    const int wv = tid >> 6, ln = tid & 63;
    if (wv == 0 && ln < Tsz) {
        // ---- LSE chunk scan, probability domain; lane = row ln of transfer matrix
        float E[81];
#pragma unroll
        for (int i = 0; i < 81; ++i) E[i] = exp2f(trans[i] * LOG2E);
        float pp[Tsz];
#pragma unroll
        for (int j = 0; j < Tsz; ++j) pp[j] = (j == ln) ? 1.0f : 0.0f;
        float K = 0.0f;
        for (int k = 1; k <= CHW; ++k) {
            if (base + k >= Ssz) break;
            const int mk = mk_w[k];
            float g[Tsz];
#pragma unroll
            for (int j = 0; j < Tsz; ++j) g[j] = pp[0] * E[j];
#pragma unroll
            for (int i = 1; i < Tsz; ++i)
#pragma unroll
                for (int j = 0; j < Tsz; ++j) g[j] = fmaf(pp[i], E[i * Tsz + j], g[j]);
#pragma unroll
            for (int j = 0; j < Tsz; ++j) {
                const float np = g[j] * exp2f(em_w[k * Tsz + j] * LOG2E);
                if (mk > 0) pp[j] = np;
            }
            if ((k & 7) == 0) {
                float ss = 0.0f;
#pragma unroll
                for (int j = 0; j < Tsz; ++j) ss += pp[j];
                K += __log2f(ss);
                const float inv = 1.0f / ss;
#pragma unroll
                for (int j = 0; j < Tsz; ++j) pp[j] *= inv;
            }
        }
        float* o = R2 + ((size_t)bc * Tsz + ln) * Tsz;
#pragma unroll
        for (int j = 0; j < Tsz; ++j) o[j] = K + __log2f(pp[j]);
    } else if (wv == 1 && ln < Tsz) {
        // ---- Viterbi max-plus chunk scan; lane = row ln
        float T[81];
#pragma unroll
        for (int i = 0; i < 81; ++i) T[i] = trans[i];
        float row[Tsz];
#pragma unroll
        for (int j = 0; j < Tsz; ++j) row[j] = (j == ln) ? 0.0f : -1e30f;
        for (int k = 1; k <= CHW; ++k) {
            if (base + k >= Ssz) break;
            const int mk = mk_w[k];
            float g[Tsz];
#pragma unroll
            for (int j = 0; j < Tsz; ++j) g[j] = row[0] + T[j];
#pragma unroll
            for (int i = 1; i < Tsz; i += 2)
#pragma unroll
                for (int j = 0; j < Tsz; ++j)
                    g[j] = fmaxf(fmaxf(g[j], row[i] + T[i * Tsz + j]),
                                 row[i + 1] + T[(i + 1) * Tsz + j]);
#pragma unroll
            for (int j = 0; j < Tsz; ++j)
                if (mk > 0) row[j] = g[j] + em_w[k * Tsz + j];
        }
        float* o = MV + (size_t)bc * 81 + ln * Tsz;
#pragma unroll
        for (int j = 0; j < Tsz; ++j) o[j] = row[j];
    } else if (wv >= 2) {
        // ---- write em window rows 0..31 to global (coalesced scalar) ----
        float* eg = em + ((size_t)b * Ssz + base) * Tsz;
        for (int i = tid - 128; i < CHW * Tsz; i += 128) eg[i] = em_w[i];
    }
}

// first-max argmax of 9 values (strict > keeps FIRST max)
__device__ __forceinline__ void amax9(const float (&v)[Tsz], float& bv, int& bi) {
    float w01v = (v[1] > v[0]) ? v[1] : v[0]; int w01i = (v[1] > v[0]) ? 1 : 0;
    float w23v = (v[3] > v[2]) ? v[3] : v[2]; int w23i = (v[3] > v[2]) ? 3 : 2;
    float w45v = (v[5] > v[4]) ? v[5] : v[4]; int w45i = (v[5] > v[4]) ? 5 : 4;
    float w67v = (v[7] > v[6]) ? v[7] : v[6]; int w67i = (v[7] > v[6]) ? 7 : 6;
    float x03v = (w23v > w01v) ? w23v : w01v; int x03i = (w23v > w01v) ? w23i : w01i;
    float x47v = (w67v > w45v) ? w67v : w45v; int x47i = (w67v > w45v) ? w67i : w45i;
    float y07v = (x47v > x03v) ? x47v : x03v; int y07i = (x47v > x03v) ? x47i : x03i;
    bv = (v[8] > y07v) ? v[8] : y07v;
    bi = (v[8] > y07v) ? 8 : y07i;
}

// ============ K2: per-batch finish + fused final reduce (last block) ============
__global__ __launch_bounds__(192, 1) void vit3_kernel(
    const float* __restrict__ em, const int* __restrict__ labels,
    const int* __restrict__ mask, const int* __restrict__ lengths,
    const float* __restrict__ start_t, const float* __restrict__ end_t,
    const float* __restrict__ trans, const float* __restrict__ R2,
    const float* __restrict__ MV, float* __restrict__ out_path,
    float* __restrict__ ll, float* __restrict__ dout, int* __restrict__ cnt) {
    __shared__ __align__(16) float em_s[4640];          // skewed [s][j]
    __shared__ __align__(16) int   mk_s[Ssz];
    __shared__ __align__(16) float mv_s[NCH * 81];
    __shared__ __align__(16) float r2_s[NCH * 81];
    __shared__ float tr_s[81];
    __shared__ float st_s[12], en_s[12];
    __shared__ __align__(16) float alc[2][NCH][12];
    __shared__ float a2c[2][12];
    __shared__ unsigned char bp[(Ssz - 1) * Tsz];
    __shared__ unsigned char mapA[64][12], mapB[64][12];
    __shared__ float den_sh, num_sh;
    __shared__ int lastf;

    const int b = blockIdx.x, tid = threadIdx.x;
    const int wv = tid >> 6, ln = tid & 63;
    const int c = tid / 12, j9 = tid % 12;
    const float* emb = em + (size_t)b * Ssz * Tsz;
    const int* mkb = mask + b * Ssz;
    const int* lbb = labels + b * Ssz;

    // ---- staging ----
    for (int i = tid; i < Ssz * Tsz; i += 192) {
        const int s = i / 9, j = i - s * 9;
        em_s[SK(s) + j] = emb[i];
    }
    for (int i = tid; i < Ssz; i += 192) mk_s[i] = mkb[i];
    {
        const float4* v4 = reinterpret_cast<const float4*>(MV + (size_t)b * NCH * 81);
        float4* vd = reinterpret_cast<float4*>(mv_s);
        for (int i = tid; i < NCH * 81 / 4; i += 192) vd[i] = v4[i];
        const float4* r4 = reinterpret_cast<const float4*>(R2 + (size_t)b * NCH * 81);
        float4* rd = reinterpret_cast<float4*>(r2_s);
        for (int i = tid; i < NCH * 81 / 4; i += 192) rd[i] = r4[i];
        if (tid < 81) tr_s[tid] = trans[tid];
        if (tid >= 96 && tid < 96 + Tsz) {
            st_s[tid - 96] = start_t[tid - 96];
            en_s[tid - 96] = end_t[tid - 96];
        }
    }
    __syncthreads();

    float tc[Tsz];
    const int jj = (j9 < Tsz) ? j9 : Tsz - 1;
#pragma unroll
    for (int i = 0; i < Tsz; ++i) tc[i] = tr_s[i * Tsz + jj];

    float aj = 0.0f;
    if (c == 0 && j9 < Tsz) {
        aj = st_s[j9] + em_s[j9];
        alc[0][0][j9] = aj;
    }
    if (wv == 1 && ln < Tsz) a2c[0][ln] = (st_s[ln] + em_s[ln]) * LOG2E;

    // ---- phase A: vit prefix chain + den combine chain (16 rounds) ----
    for (int r = 0; r < NCH; ++r) {
        __syncthreads();
        if (r < NCH - 1 && c == r + 1 && j9 < Tsz) {
            const float* M = &mv_s[r * 81];
            float m = alc[0][r][0] + M[j9];
#pragma unroll
            for (int i = 1; i < Tsz; ++i)
                m = fmaxf(m, alc[0][r][i] + M[i * Tsz + j9]);
            aj = m;
            alc[0][c][j9] = m;
        }
        if (wv == 1 && ln < Tsz) {
            const float* Rr = &r2_s[r * 81];
            float xi[Tsz];
#pragma unroll
            for (int i = 0; i < Tsz; ++i) xi[i] = a2c[r & 1][i] + Rr[i * Tsz + ln];
            float m = xi[0];
#pragma unroll
            for (int i = 1; i < Tsz; ++i) m = fmaxf(m, xi[i]);
            float sm = 0.0f;
#pragma unroll
            for (int i = 0; i < Tsz; ++i) sm += exp2f(xi[i] - m);
            a2c[(r + 1) & 1][ln] = m + __log2f(sm);
        }
    }

    // ---- phase B: chunk-parallel viterbi scan (32 barrier-steps) ----
    int pb = 0;
    for (int k = 0; k < 32; ++k) {
        __syncthreads();
        const int s = c * 32 + 1 + k;
        if (j9 < Tsz && s <= Ssz - 1) {
            const int mk = mk_s[s];
            float av[12];
            const float4* ap = reinterpret_cast<const float4*>(&alc[pb][c][0]);
            *reinterpret_cast<float4*>(&av[0]) = ap[0];
            *reinterpret_cast<float4*>(&av[4]) = ap[1];
            *reinterpret_cast<float4*>(&av[8]) = ap[2];
            float v[Tsz];
#pragma unroll
            for (int i = 0; i < Tsz; ++i) v[i] = av[i] + tc[i];
            float bv; int bi;
            amax9(v, bv, bi);
            bp[(s - 1) * Tsz + j9] = (unsigned char)((mk > 0) ? bi : j9);
            if (mk > 0) aj = bv + em_s[SK(s) + j9];
        }
        if (j9 < Tsz) alc[1 - pb][c][j9] = aj;
        pb ^= 1;
    }
    __syncthreads();

    // ---- last tag (redundant per-thread) ----
    float bb = alc[0][NCH - 1][0] + en_s[0];
    int last = 0;
#pragma unroll
    for (int q = 1; q < Tsz; ++q) {
        const float qq = alc[0][NCH - 1][q] + en_s[q];
        if (qq > bb) { bb = qq; last = q; }
    }

    // ---- S1: wave0 chunk maps, wave1 den final, wave2 numerator ----
    const int lo = ln * 8;
    const int hi = min(lo + 7, Ssz - 2);
    if (wv == 0) {
        int xf[Tsz];
#pragma unroll
        for (int t = 0; t < Tsz; ++t) xf[t] = t;
        for (int k = hi; k >= lo; --k) {
#pragma unroll
            for (int t = 0; t < Tsz; ++t) xf[t] = bp[k * Tsz + xf[t]];
        }
#pragma unroll
        for (int t = 0; t < Tsz; ++t) mapA[ln][t] = (unsigned char)xf[t];
    } else if (wv == 1) {
        if (ln == 0) {
            float xv[Tsz];
#pragma unroll
            for (int i = 0; i < Tsz; ++i) xv[i] = a2c[0][i] + en_s[i] * LOG2E;
            float m = xv[0];
#pragma unroll
            for (int i = 1; i < Tsz; ++i) m = fmaxf(m, xv[i]);
            float sm = 0.0f;
#pragma unroll
            for (int i = 0; i < Tsz; ++i) sm += exp2f(xv[i] - m);
            den_sh = m + __log2f(sm);
        }
    } else {
        float part = 0.0f;
        for (int s = 1 + ln; s < Ssz; s += 64) {
            if (mk_s[s] > 0) {
                const int tg = lbb[s];
                int pq = s - 1;
                while (pq > 0 && mk_s[pq] == 0) --pq;
                part += tr_s[lbb[pq] * Tsz + tg] + em_s[SK(s) + tg];
            }
        }
#pragma unroll
        for (int off = 32; off >= 1; off >>= 1) part += __shfl_xor(part, off, 64);
        if (ln == 0) {
            const int tg0 = lbb[0];
            float num = part + st_s[tg0] + em_s[tg0];
            int pq = Ssz - 1;
            while (pq > 0 && mk_s[pq] == 0) --pq;
            num += en_s[lbb[pq]];
            num_sh = num;
        }
    }

    // ---- suffix-composition doubling ----
#define VIT_RND(CUR, NXT, D)                                               \
    {                                                                      \
        unsigned char nn[Tsz];                                             \
        if (wv == 0) {                                                     \
            const int o = ln + (D);                                        \
            if (o < 64) {                                                  \
                _Pragma("unroll") for (int t = 0; t < Tsz; ++t)            \
                    nn[t] = CUR[ln][CUR[o][t]];                            \
            } else {                                                       \
                _Pragma("unroll") for (int t = 0; t < Tsz; ++t)            \
                    nn[t] = CUR[ln][t];                                    \
            }                                                              \
        }                                                                  \
        __syncthreads();                                                   \
        if (wv == 0) {                                                     \
            _Pragma("unroll") for (int t = 0; t < Tsz; ++t)                \
                NXT[ln][t] = nn[t];                                        \
        }                                                                  \
        __syncthreads();                                                   \
    }
    VIT_RND(mapA, mapB, 1)
    VIT_RND(mapB, mapA, 2)
    VIT_RND(mapA, mapB, 4)
    VIT_RND(mapB, mapA, 8)
    VIT_RND(mapA, mapB, 16)
    VIT_RND(mapB, mapA, 32)
#undef VIT_RND

    if (wv == 0) {
        int t = (ln == 63) ? last : (int)mapA[ln + 1][last];
        float* op = out_path + (size_t)b * Ssz;
        for (int k = hi; k >= lo; --k) {
            t = bp[k * Tsz + t];
            op[k] = (float)t;
        }
        if (ln == 0) op[Ssz - 1] = (float)last;
    }
    if (b == 0 && wv == 2) dout[1 + Bsz * Ssz + ln] = (float)lengths[ln];

    // ---- fused final reduce: last block sums ll -> loss ----
    if (tid == 0) {
        ll[b] = num_sh - den_sh * LN2F;
        __threadfence();
        lastf = (atomicAdd(cnt, 1) == Bsz - 1) ? 1 : 0;
    }
    __syncthreads();
    if (lastf && wv == 0) {
        __threadfence();
        float v = ll[ln];
#pragma unroll
        for (int off = 32; off >= 1; off >>= 1) v += __shfl_xor(v, off, 64);
        if (ln == 0) dout[0] = -v * (1.0f / (float)Bsz);
    }
}

extern "C" void kernel_launch(void* const* d_in, const int* in_sizes, int n_in,
                              void* d_out, int out_size, void* d_ws, size_t ws_size,
                              hipStream_t stream) {
    const float* enc    = (const float*)d_in[0];
    const int*   labels = (const int*)d_in[1];
    const int*   mask   = (const int*)d_in[2];
    const int*   lengths= (const int*)d_in[3];
    const float* fcw    = (const float*)d_in[4];
    const float* fcb    = (const float*)d_in[5];
    const float* startt = (const float*)d_in[6];
    const float* endt   = (const float*)d_in[7];
    const float* trans  = (const float*)d_in[8];

    float* out = (float*)d_out;
    float* em  = (float*)d_ws;                                // 294912 f
    float* R2  = em + (size_t)Bsz * Ssz * Tsz;                // 82944 f
    float* MV  = R2 + (size_t)Bsz * NCH * 81;                 // 82944 f
    float* ll  = MV + (size_t)Bsz * NCH * 81;                 // 64 f
    int*   cnt = (int*)(ll + Bsz);                            // 1 int

    emscan_kernel<<<Bsz * NCH, 256, 0, stream>>>(enc, fcw, fcb, mask, trans,
                                                 em, R2, MV, cnt);
    vit3_kernel<<<Bsz, 192, 0, stream>>>(em, labels, mask, lengths, startt, endt,
                                         trans, R2, MV, out + 1, ll, out, cnt);
}